// Round 21
// baseline (169.811 us; speedup 1.0000x reference)
//
#include <hip/hip_runtime.h>
#include <hip/hip_bf16.h>
#include <math.h>

// Problem constants (Qwen2MoeAttention, T=2048)
#define TSEQ   2048
#define HID    2048
#define NH     16
#define NKV    4
#define HD     128
#define KVD    512
#define SCALING 0.08838834764831845f   // 1/sqrt(128)
#define LOG2E  1.4426950408889634f
#define ROPE_C1 0.31143075889569023f   // log2(1e6)/64
#define ROPE_C2 2.6514961294723187f    // log2(2*pi)

typedef float f4  __attribute__((ext_vector_type(4),  aligned(16)));
typedef float f16v __attribute__((ext_vector_type(16), aligned(64)));
typedef short s8v __attribute__((ext_vector_type(8),  aligned(16)));
typedef short s4v __attribute__((ext_vector_type(4),  aligned(8)));

__device__ __forceinline__ short f2bf(float x) {
    union { __hip_bfloat16 b; short s; } u;
    u.b = __float2bfloat16(x);
    return u.s;
}
__device__ __forceinline__ float bf2f(short s) {
    union { unsigned u; float f; } v;
    v.u = ((unsigned)(unsigned short)s) << 16;
    return v.f;
}
// truncation pack of two NON-NEGATIVE floats to packed bf16 (3 ops)
__device__ __forceinline__ unsigned pk2t(float a, float b) {
    union { float f; unsigned u; } ua, ub;
    ua.f = a; ub.f = b;
    return (ub.u & 0xFFFF0000u) | (ua.u >> 16);
}
__device__ __forceinline__ void gl_lds16(const void* g, void* l) {
    __builtin_amdgcn_global_load_lds(
        (const __attribute__((address_space(1))) void*)g,
        (__attribute__((address_space(3))) void*)l, 16, 0, 0);
}
// RoPE angle via revolutions + sinpi/cospi (cheap, ~1e-4 rad class like f32 ref)
__device__ __forceinline__ void rope_sc(float p, float jf, float& s, float& c) {
    const float rev = p * exp2f(-(jf * ROPE_C1 + ROPE_C2));
    const float f2 = 2.0f * (rev - floorf(rev));
    s = sinpif(f2);
    c = cospif(f2);
}

// ---------------------------------------------------------------------------
// f32 -> bf16 bulk convert (hidden_states), 8 elems/thread
// ---------------------------------------------------------------------------
__global__ __launch_bounds__(256) void f32_to_bf16(
    const float* __restrict__ in, short* __restrict__ out)
{
    const int i = (blockIdx.x * 256 + threadIdx.x) * 8;
    f4 a = *(const f4*)(in + i);
    f4 b = *(const f4*)(in + i + 4);
    s8v v;
    v[0] = f2bf(a[0]); v[1] = f2bf(a[1]); v[2] = f2bf(a[2]); v[3] = f2bf(a[3]);
    v[4] = f2bf(b[0]); v[5] = f2bf(b[1]); v[6] = f2bf(b[2]); v[7] = f2bf(b[3]);
    *(s8v*)(out + i) = v;
}

// ---------------------------------------------------------------------------
// MERGED Q/K/V GPTQ GEMM (16x16x32 MFMA) — R16/R20 form. Per-block routing:
// bc<32 -> q (bf16 row, Qg); bc<40 -> k (bf16 row, Kg, pre-rope); else -> v
// (bf16 transposed, Vtg). Grid (48,16) = 768 blocks = 3/CU.
// ---------------------------------------------------------------------------
__global__ __launch_bounds__(256) void gemm_qkv(
    const short* __restrict__ X,
    const int* __restrict__ q_qw, const float* __restrict__ q_sc, const int* __restrict__ q_zr,
    const int* __restrict__ k_qw, const float* __restrict__ k_sc, const int* __restrict__ k_zr,
    const int* __restrict__ v_qw, const float* __restrict__ v_sc, const int* __restrict__ v_zr,
    short* __restrict__ Qg, short* __restrict__ Kg, short* __restrict__ Vtg)
{
    constexpr int BM = 128, BN = 64;
    constexpr int WM = BM / 2, WN = BN / 2, FM = WM / 16, FN = WN / 16;
    __shared__ __align__(16) short As[BM * 64];
    __shared__ __align__(16) short Bs[BN * 64];
    const int tid = threadIdx.x;
    const int l = tid & 63, w = tid >> 6;
    const int l15 = l & 15, l4 = l >> 4;
    const int wr = w >> 1, wc = w & 1;
    const int br = blockIdx.y, bcx = blockIdx.x;

    const int* qw; const float* scales; const int* zeros;
    int OUT, bc, vmode; short* dst;
    if (bcx < 32)      { qw = q_qw; scales = q_sc; zeros = q_zr; OUT = 2048; bc = bcx;      vmode = 0; dst = Qg;  }
    else if (bcx < 40) { qw = k_qw; scales = k_sc; zeros = k_zr; OUT = 512;  bc = bcx - 32; vmode = 0; dst = Kg;  }
    else               { qw = v_qw; scales = v_sc; zeros = v_zr; OUT = 512;  bc = bcx - 40; vmode = 1; dst = Vtg; }

    const int colB = tid % BN;
    const int colg = bc * BN + colB;
    const int prb  = (tid / BN) * (BN / 32);

    f4 acc[FM][FN] = {};

    for (int kt = 0; kt < 32; ++kt) {
        __syncthreads();
        #pragma unroll
        for (int n = 0; n < BM / 32; ++n) {
            int s = n * 256 + tid;            // 16B-unit index
            int r = s >> 3, up = s & 7;
            int u = up ^ (r & 7);
            gl_lds16(X + (size_t)(br * BM + r) * 2048 + kt * 64 + u * 8,
                     &As[(n * 256 + (tid & ~63)) * 8]);
        }
        {
            const int g = kt >> 1;
            const float sc = scales[g * OUT + colg];
            const float zf = (float)zeros[g * OUT + colg];
            #pragma unroll
            for (int n = 0; n < BN / 32; ++n) {
                int pr = prb + n;
                unsigned p = (unsigned)qw[(kt * 8 + pr) * OUT + colg];
                s8v bv;
                #pragma unroll
                for (int s = 0; s < 8; ++s) {
                    float qv = (float)((p >> (4 * s)) & 15u);
                    bv[s] = f2bf((qv - zf) * sc);
                }
                *(s8v*)(&Bs[colB * 64 + ((pr * 8) ^ ((colB & 7) << 3))]) = bv;
            }
        }
        __syncthreads();
        #pragma unroll
        for (int ks = 0; ks < 2; ++ks) {
            s8v a[FM], b[FN];
            #pragma unroll
            for (int m_ = 0; m_ < FM; ++m_) {
                int row = wr * WM + m_ * 16 + l15;
                a[m_] = *(const s8v*)(&As[row * 64 + ((ks * 32 + l4 * 8) ^ ((row & 7) << 3))]);
            }
            #pragma unroll
            for (int n_ = 0; n_ < FN; ++n_) {
                int col = wc * WN + n_ * 16 + l15;
                b[n_] = *(const s8v*)(&Bs[col * 64 + ((ks * 32 + l4 * 8) ^ ((col & 7) << 3))]);
            }
            __builtin_amdgcn_s_setprio(1);
            #pragma unroll
            for (int m_ = 0; m_ < FM; ++m_)
                #pragma unroll
                for (int n_ = 0; n_ < FN; ++n_)
                    acc[m_][n_] = __builtin_amdgcn_mfma_f32_16x16x32_bf16(
                        a[m_], b[n_], acc[m_][n_], 0, 0, 0);
            __builtin_amdgcn_s_setprio(0);
        }
    }
    if (vmode == 0) {
        #pragma unroll
        for (int m_ = 0; m_ < FM; ++m_)
            #pragma unroll
            for (int n_ = 0; n_ < FN; ++n_)
                #pragma unroll
                for (int r = 0; r < 4; ++r)
                    dst[(size_t)(br * BM + wr * WM + m_ * 16 + l4 * 4 + r) * OUT
                        + bc * BN + wc * WN + n_ * 16 + l15] = f2bf(acc[m_][n_][r]);
    } else {
        #pragma unroll
        for (int m_ = 0; m_ < FM; ++m_)
            #pragma unroll
            for (int n_ = 0; n_ < FN; ++n_) {
                int col  = bc * BN + wc * WN + n_ * 16 + l15;
                int row0 = br * BM + wr * WM + m_ * 16 + l4 * 4;
                s4v pk;
                #pragma unroll
                for (int r = 0; r < 4; ++r) pk[r] = f2bf(acc[m_][n_][r]);
                *(s4v*)(&dst[(size_t)col * TSEQ + row0]) = pk;
            }
    }
}

// ---------------------------------------------------------------------------
// O-projection GPTQ GEMM (16x16x32), f32 row-major out — R16/R20 form.
// ---------------------------------------------------------------------------
__global__ __launch_bounds__(256) void gemm_o(
    const short* __restrict__ X, const int* __restrict__ qw,
    const float* __restrict__ scales, const int* __restrict__ zeros,
    float* __restrict__ Y, int OUT)
{
    constexpr int BM = 128, BN = 64;
    constexpr int WM = BM / 2, WN = BN / 2, FM = WM / 16, FN = WN / 16;
    __shared__ __align__(16) short As[BM * 64];
    __shared__ __align__(16) short Bs[BN * 64];
    const int tid = threadIdx.x;
    const int l = tid & 63, w = tid >> 6;
    const int l15 = l & 15, l4 = l >> 4;
    const int wr = w >> 1, wc = w & 1;
    const int br = blockIdx.y, bc = blockIdx.x;

    const int colB = tid % BN;
    const int colg = bc * BN + colB;
    const int prb  = (tid / BN) * (BN / 32);

    f4 acc[FM][FN] = {};

    for (int kt = 0; kt < 32; ++kt) {
        __syncthreads();
        #pragma unroll
        for (int n = 0; n < BM / 32; ++n) {
            int s = n * 256 + tid;
            int r = s >> 3, up = s & 7;
            int u = up ^ (r & 7);
            gl_lds16(X + (size_t)(br * BM + r) * 2048 + kt * 64 + u * 8,
                     &As[(n * 256 + (tid & ~63)) * 8]);
        }
        {
            const int g = kt >> 1;
            const float sc = scales[g * OUT + colg];
            const float zf = (float)zeros[g * OUT + colg];
            #pragma unroll
            for (int n = 0; n < BN / 32; ++n) {
                int pr = prb + n;
                unsigned p = (unsigned)qw[(kt * 8 + pr) * OUT + colg];
                s8v bv;
                #pragma unroll
                for (int s = 0; s < 8; ++s) {
                    float qv = (float)((p >> (4 * s)) & 15u);
                    bv[s] = f2bf((qv - zf) * sc);
                }
                *(s8v*)(&Bs[colB * 64 + ((pr * 8) ^ ((colB & 7) << 3))]) = bv;
            }
        }
        __syncthreads();
        #pragma unroll
        for (int ks = 0; ks < 2; ++ks) {
            s8v a[FM], b[FN];
            #pragma unroll
            for (int m_ = 0; m_ < FM; ++m_) {
                int row = wr * WM + m_ * 16 + l15;
                a[m_] = *(const s8v*)(&As[row * 64 + ((ks * 32 + l4 * 8) ^ ((row & 7) << 3))]);
            }
            #pragma unroll
            for (int n_ = 0; n_ < FN; ++n_) {
                int col = wc * WN + n_ * 16 + l15;
                b[n_] = *(const s8v*)(&Bs[col * 64 + ((ks * 32 + l4 * 8) ^ ((col & 7) << 3))]);
            }
            __builtin_amdgcn_s_setprio(1);
            #pragma unroll
            for (int m_ = 0; m_ < FM; ++m_)
                #pragma unroll
                for (int n_ = 0; n_ < FN; ++n_)
                    acc[m_][n_] = __builtin_amdgcn_mfma_f32_16x16x32_bf16(
                        a[m_], b[n_], acc[m_][n_], 0, 0, 0);
            __builtin_amdgcn_s_setprio(0);
        }
    }
    #pragma unroll
    for (int m_ = 0; m_ < FM; ++m_)
        #pragma unroll
        for (int n_ = 0; n_ < FN; ++n_)
            #pragma unroll
            for (int r = 0; r < 4; ++r)
                Y[(size_t)(br * BM + wr * WM + m_ * 16 + l4 * 4 + r) * OUT
                  + bc * BN + wc * WN + n_ * 16 + l15] = acc[m_][n_][r];
}

// ---------------------------------------------------------------------------
// RoPE (NeoX): Q and K in-place on bf16 (Q additionally prescaled by
// SCALING*LOG2E).
// ---------------------------------------------------------------------------
__global__ __launch_bounds__(256) void rope_qk(
    const int* __restrict__ pos, short* __restrict__ Qg, short* __restrict__ Kg)
{
    const int t = blockIdx.x;
    const int tid = threadIdx.x;
    const int j = tid & 63;
    const int g = tid >> 6;
    const float p = (float)pos[t];
    float s, c;
    rope_sc(p, (float)j, s, c);
    const float QS = SCALING * LOG2E;
    #pragma unroll
    for (int n = 0; n < 4; ++n) {
        int h = g * 4 + n;
        short* base = Qg + (size_t)t * 2048 + h * 128;
        float x1 = bf2f(base[j]), x2 = bf2f(base[j + 64]);
        base[j]      = f2bf((x1 * c - x2 * s) * QS);
        base[j + 64] = f2bf((x2 * c + x1 * s) * QS);
    }
    {
        short* base = Kg + (size_t)t * 512 + g * 128;
        float x1 = bf2f(base[j]), x2 = bf2f(base[j + 64]);
        base[j]      = f2bf(x1 * c - x2 * s);
        base[j + 64] = f2bf(x2 * c + x1 * s);
    }
}

// ---------------------------------------------------------------------------
// Swapped-operand 32x32 MFMA flash attention, V-DIRECT-FROM-L2 variant:
// only K is LDS-staged (dbuf 2x16KB = 32KB -> residency cap rises); V
// fragments are loaded straight from Vtg (L2-resident, 512KB/kvh), groups
// s={0,1} issued before softmax (~300cyc cover), s={2,3} prefetched under
// the s={0,1} MFMAs. K-SPLIT=4 -> 1024 blocks so the raised cap is used;
// balanced mapping: co-resident {u,u+16,u+32,u+48} -> jts {63-u,47-u,u,u+16}
// -> chunk-sum 67 = constant. Partial z=3 lives in d_out (combine4 reads
// before gemm_o overwrites; R17-validated). Q pre-roped; T13 defer-max;
// T5 setprio; diag skip; trunc P-pack. launch_bounds(256,2) (never force).
// D layout (32x32): col=lane&31, row=(reg&3)+8*(reg>>2)+4*(lane>>5).
// ---------------------------------------------------------------------------
__global__ __launch_bounds__(256, 2) void attn4w(
    const short* __restrict__ Qg, const short* __restrict__ Kg,
    const short* __restrict__ Vtg, short* __restrict__ Op0,
    short* __restrict__ Op1, short* __restrict__ Op2,
    short* __restrict__ Op3, float2* __restrict__ stats)
{
    __shared__ __align__(16) short Ks[2][64 * 128];   // 2 x 16KB (K only)

    const int tid = threadIdx.x;
    const int l = tid & 63, w = tid >> 6;
    const int h = l >> 5, q = l & 31;
    const int f = blockIdx.x;             // flat 0..1023
    const int z = f & 3;
    const int kvh = (f >> 2) & 3;
    const int u = f >> 4;                 // 0..63
    const int jt = (u < 32) ? (63 - u) : (u - 32);
    const int q0 = jt * 32;
    const int head = kvh * 4 + w;
    const int row = q0 + q;

    const int nch = (jt >> 1) + 1;        // 64-key chunks for this tile
    const int c0 = (nch * z) >> 2;
    const int c1 = (nch * (z + 1)) >> 2;

    // --- Q fragments: pre-roped, pre-scaled (log2 domain) ---
    s8v qf[8];
    {
        const short* qp = Qg + (size_t)row * 2048 + head * 128 + h * 8;
        #pragma unroll
        for (int d8 = 0; d8 < 8; ++d8) qf[d8] = *(const s8v*)(qp + d8 * 16);
    }

    // per-lane V row base: row (kvh*128 + q + dt*32), byte-unit h within s
    const short* vrow0 = Vtg + (size_t)(kvh * 128 + q) * TSEQ + h * 8;

    f16v O[4];
    #pragma unroll
    for (int dt = 0; dt < 4; ++dt)
        #pragma unroll
        for (int r = 0; r < 16; ++r) O[dt][r] = 0.0f;
    float m = -1e30f, lsum = 0.0f;

    if (c0 < c1) {
        // ---- hoisted per-thread K staging sources ----
        const short* kS[4]; int kD[4];
        #pragma unroll
        for (int n4 = 0; n4 < 4; ++n4) {
            int n = w * 4 + n4;
            int s = n * 64 + l;              // K 16B-unit index
            int r = s >> 4, uu = (s & 15) ^ (r & 15);
            kS[n4] = Kg + ((size_t)(c0 * 64 + r) * 512 + kvh * 128 + uu * 8);
            kD[n4] = n * 512;
        }
        auto STAGE = [&](int b, int adv) {
            #pragma unroll
            for (int n4 = 0; n4 < 4; ++n4)
                gl_lds16(kS[n4] + (size_t)adv * 32768, &Ks[b][kD[n4]]);
        };

        STAGE(0, 0);
        int cur = 0;
        for (int kc = c0; kc < c1; ++kc) {
            const int k0 = kc * 64;
            __syncthreads();   // staged K visible; prev buffer free
            if (kc + 1 < c1) STAGE(cur ^ 1, kc + 1 - c0);

            const bool diag  = (kc == nch - 1);
            const bool skip1 = diag && ((jt & 1) == 0);  // upper 32 keys all masked

            // --- QK^T swapped: pD[t] = S[k-tile t][q-row] ---
            f16v pD[2];
            #pragma unroll
            for (int t = 0; t < 2; ++t)
                #pragma unroll
                for (int r = 0; r < 16; ++r) pD[t][r] = 0.0f;
            __builtin_amdgcn_s_setprio(1);
            #pragma unroll
            for (int d8 = 0; d8 < 8; ++d8) {
                s8v kf = *(const s8v*)(
                    &Ks[cur][(q * 16 + ((d8 * 2 + h) ^ (q & 15))) * 8]);
                pD[0] = __builtin_amdgcn_mfma_f32_32x32x16_bf16(kf, qf[d8], pD[0], 0, 0, 0);
            }
            if (!skip1) {
                #pragma unroll
                for (int d8 = 0; d8 < 8; ++d8) {
                    int r = 32 + q;
                    s8v kf = *(const s8v*)(
                        &Ks[cur][(r * 16 + ((d8 * 2 + h) ^ (r & 15))) * 8]);
                    pD[1] = __builtin_amdgcn_mfma_f32_32x32x16_bf16(kf, qf[d8], pD[1], 0, 0, 0);
                }
            }
            __builtin_amdgcn_s_setprio(0);
            // --- V prefetch groups s=0,1 (latency hidden under softmax) ---
            const short* vrow = vrow0 + k0;
            s8v vA[4], vB[4];
            #pragma unroll
            for (int dt = 0; dt < 4; ++dt) {
                vA[dt] = *(const s8v*)(vrow + (size_t)dt * 32 * TSEQ);
                vB[dt] = *(const s8v*)(vrow + (size_t)dt * 32 * TSEQ + 16);
            }
            if (skip1) {
                #pragma unroll
                for (int r = 0; r < 16; ++r) pD[1][r] = -1e30f;
            }
            // --- causal mask (global last chunk; only the z covering it) ---
            if (diag) {
                #pragma unroll
                for (int t = 0; t < 2; ++t)
                    #pragma unroll
                    for (int r = 0; r < 16; ++r) {
                        int koff = (r & 3) + 8 * (r >> 2) + 4 * h + 32 * t;
                        if (k0 + koff > row) pD[t][r] = -1e30f;
                    }
            }
            // --- row max: lane-local tree + one cross-half shfl ---
            float mx = pD[0][0];
            #pragma unroll
            for (int r = 1; r < 16; ++r) mx = fmaxf(mx, pD[0][r]);
            #pragma unroll
            for (int r = 0; r < 16; ++r) mx = fmaxf(mx, pD[1][r]);
            mx = fmaxf(mx, __shfl_xor(mx, 32, 64));
            // --- T13 defer-max ---
            if (__any(mx - m > 8.0f)) {
                const float mn = fmaxf(m, mx);
                const float sc = exp2f(m - mn);
                #pragma unroll
                for (int dt = 0; dt < 4; ++dt)
                    #pragma unroll
                    for (int r = 0; r < 16; ++r) O[dt][r] *= sc;
                lsum *= sc;
                m = mn;
            }
            // --- P = exp2(S - m) (bounded by 2^8), row sum ---
            float rs = 0.0f;
            #pragma unroll
            for (int t = 0; t < 2; ++t)
                #pragma unroll
                for (int r = 0; r < 16; ++r) {
                    float pv = exp2f(pD[t][r] - m);
                    pD[t][r] = pv;
                    rs += pv;
                }
            rs += __shfl_xor(rs, 32, 64);
            lsum += rs;
            // --- pack P -> bf16 B-fragments (trunc pack, quad exchange) ---
            s8v pf[4];
            #pragma unroll
            for (int s = 0; s < 4; ++s) {
                const int t = s >> 1, c = s & 1;
                const int bk = 8 * c + 4 * h;
                const int bs = 8 * c + 4 * (1 - h);
                unsigned kp0 = pk2t(pD[t][bk + 0], pD[t][bk + 1]);
                unsigned kp1 = pk2t(pD[t][bk + 2], pD[t][bk + 3]);
                unsigned sp0 = pk2t(pD[t][bs + 0], pD[t][bs + 1]);
                unsigned sp1 = pk2t(pD[t][bs + 2], pD[t][bs + 3]);
                unsigned r0 = __shfl_xor((int)sp0, 32, 64);
                unsigned r1 = __shfl_xor((int)sp1, 32, 64);
                union { unsigned u[4]; s8v v; } fr;
                fr.u[0] = h ? r0 : kp0;
                fr.u[1] = h ? r1 : kp1;
                fr.u[2] = h ? kp0 : r0;
                fr.u[3] = h ? kp1 : r1;
                pf[s] = fr.v;
            }
            // --- PV swapped (V direct): s=0 (vA), s=1 (vB); s=2,3 prefetched
            //     into vA/vB under the s=0/1 MFMAs ---
            __builtin_amdgcn_s_setprio(1);
            #pragma unroll
            for (int dt = 0; dt < 4; ++dt)
                O[dt] = __builtin_amdgcn_mfma_f32_32x32x16_bf16(vA[dt], pf[0], O[dt], 0, 0, 0);
            if (!skip1) {
                #pragma unroll
                for (int dt = 0; dt < 4; ++dt)
                    vA[dt] = *(const s8v*)(vrow + (size_t)dt * 32 * TSEQ + 32);
            }
            #pragma unroll
            for (int dt = 0; dt < 4; ++dt)
                O[dt] = __builtin_amdgcn_mfma_f32_32x32x16_bf16(vB[dt], pf[1], O[dt], 0, 0, 0);
            if (!skip1) {
                #pragma unroll
                for (int dt = 0; dt < 4; ++dt)
                    vB[dt] = *(const s8v*)(vrow + (size_t)dt * 32 * TSEQ + 48);
                #pragma unroll
                for (int dt = 0; dt < 4; ++dt)
                    O[dt] = __builtin_amdgcn_mfma_f32_32x32x16_bf16(vA[dt], pf[2], O[dt], 0, 0, 0);
                #pragma unroll
                for (int dt = 0; dt < 4; ++dt)
                    O[dt] = __builtin_amdgcn_mfma_f32_32x32x16_bf16(vB[dt], pf[3], O[dt], 0, 0, 0);
            }
            __builtin_amdgcn_s_setprio(0);
            cur ^= 1;
        }
    }

    // --- epilogue: UNNORMALIZED partial O (bf16) + stats ---
    short* Opz = (z == 0) ? Op0 : (z == 1) ? Op1 : (z == 2) ? Op2 : Op3;
    #pragma unroll
    for (int dt = 0; dt < 4; ++dt)
        #pragma unroll
        for (int g2 = 0; g2 < 4; ++g2) {
            int d4 = dt * 32 + 8 * g2 + 4 * h;
            s4v ov;
            #pragma unroll
            for (int r = 0; r < 4; ++r) ov[r] = f2bf(O[dt][g2 * 4 + r]);
            *(s4v*)(Opz + (size_t)row * 2048 + head * 128 + d4) = ov;
        }
    if (h == 0)
        stats[((size_t)z * NH + head) * TSEQ + row] = make_float2(m, lsum);
}

// ---------------------------------------------------------------------------
// Combine the four K-split partials. out may alias Op0 (same-thread,
// same-address read-before-write). Empty splits: m=-1e30 -> weight 0.
// ---------------------------------------------------------------------------
__global__ __launch_bounds__(256) void attn_combine4(
    const short* __restrict__ Op0, const short* __restrict__ Op1,
    const short* __restrict__ Op2, const short* __restrict__ Op3,
    const float2* __restrict__ stats, short* __restrict__ out)
{
    const int gp = blockIdx.x * 16 + (threadIdx.x >> 4);   // row*16 + head
    const int row = gp >> 4;
    const int head = gp & 15;
    const int d0 = (threadIdx.x & 15) * 8;
    const float2 s0 = stats[(size_t)head * TSEQ + row];
    const float2 s1 = stats[((size_t)NH + head) * TSEQ + row];
    const float2 s2 = stats[((size_t)2 * NH + head) * TSEQ + row];
    const float2 s3 = stats[((size_t)3 * NH + head) * TSEQ + row];
    const float M = fmaxf(fmaxf(s0.x, s1.x), fmaxf(s2.x, s3.x));
    const float w0 = exp2f(s0.x - M), w1 = exp2f(s1.x - M);
    const float w2 = exp2f(s2.x - M), w3 = exp2f(s3.x - M);
    const float inv = 1.0f / (s0.y * w0 + s1.y * w1 + s2.y * w2 + s3.y * w3);
    const size_t off = (size_t)row * 2048 + head * 128 + d0;
    s8v a = *(const s8v*)(Op0 + off);
    s8v b = *(const s8v*)(Op1 + off);
    s8v c = *(const s8v*)(Op2 + off);
    s8v d = *(const s8v*)(Op3 + off);
    s8v o;
    #pragma unroll
    for (int j = 0; j < 8; ++j)
        o[j] = f2bf((bf2f(a[j]) * w0 + bf2f(b[j]) * w1 +
                     bf2f(c[j]) * w2 + bf2f(d[j]) * w3) * inv);
    *(s8v*)(out + off) = o;
}

// ---------------------------------------------------------------------------
extern "C" void kernel_launch(void* const* d_in, const int* in_sizes, int n_in,
                              void* d_out, int out_size, void* d_ws, size_t ws_size,
                              hipStream_t stream)
{
    const int*   positions = (const int*)  d_in[0];
    const float* hidden    = (const float*)d_in[1];
    const int*   q_qw = (const int*)  d_in[2];
    const float* q_sc = (const float*)d_in[3];
    const int*   q_zr = (const int*)  d_in[4];
    const int*   k_qw = (const int*)  d_in[5];
    const float* k_sc = (const float*)d_in[6];
    const int*   k_zr = (const int*)  d_in[7];
    const int*   v_qw = (const int*)  d_in[8];
    const float* v_sc = (const float*)d_in[9];
    const int*   v_zr = (const int*)  d_in[10];
    const int*   o_qw = (const int*)  d_in[11];
    const float* o_sc = (const float*)d_in[12];
    const int*   o_zr = (const int*)  d_in[13];
    float* outf = (float*)d_out;

    // workspace (40 MB), lifetime-based aliasing:
    //  [0,8M):   Qg bf16[T,2048]  (gemm_qkv out; rope_qk in-place; attn in)
    //  [8,16M):  Op0 bf16 (attn partial z0) -> abuf (combine out, in-place)
    //  [16,17M): stats float2[4][NH][T]
    //  [20,28M): hb bf16[2048,2048] (dead after gemm_qkv) -> Op1
    //  [28,30M): Kg bf16[T,512]   (gemm_qkv out, rope_qk in-place)
    //  [30,32M): Vtg bf16[512,T]  (gemm_qkv transposed out)
    //  [32,40M): Op2
    //  Op3 = first 8MB of d_out (read by combine4 BEFORE gemm_o overwrites)
    char* base = (char*)d_ws;
    short* Qg   = (short*)(base);
    short* Op0  = (short*)(base + (8u << 20));
    short* abuf = Op0;
    float2* stats = (float2*)(base + (16u << 20));
    short* hb   = (short*)(base + (20u << 20));
    short* Op1  = (short*)(base + (20u << 20));
    short* Kg   = (short*)(base + (28u << 20));
    short* Vtg  = (short*)(base + (30u << 20));
    short* Op2  = (short*)(base + (32u << 20));
    short* Op3  = (short*)d_out;

    dim3 blk(256);
    f32_to_bf16<<<dim3(2048), blk, 0, stream>>>(hidden, hb);
    gemm_qkv<<<dim3(48, 16), blk, 0, stream>>>(hb,
        q_qw, q_sc, q_zr, k_qw, k_sc, k_zr, v_qw, v_sc, v_zr, Qg, Kg, Vtg);
    rope_qk<<<dim3(TSEQ), blk, 0, stream>>>(positions, Qg, Kg);
    attn4w<<<dim3(1024), blk, 0, stream>>>(Qg, Kg, Vtg, Op0, Op1, Op2, Op3, stats);
    attn_combine4<<<dim3(TSEQ * NH / 16), blk, 0, stream>>>(Op0, Op1, Op2, Op3, stats, abuf);
    gemm_o<<<dim3(32, 16), blk, 0, stream>>>(abuf, o_qw, o_sc, o_zr, outf, 2048);
}

// Round 22
// 167.267 us; speedup vs baseline: 1.0152x; 1.0152x over previous
//
#include <hip/hip_runtime.h>
#include <hip/hip_bf16.h>
#include <math.h>

// Problem constants (Qwen2MoeAttention, T=2048)
#define TSEQ   2048
#define HID    2048
#define NH     16
#define NKV    4
#define HD     128
#define KVD    512
#define SCALING 0.08838834764831845f   // 1/sqrt(128)
#define LOG2E  1.4426950408889634f
#define ROPE_C1 0.31143075889569023f   // log2(1e6)/64
#define ROPE_C2 2.6514961294723187f    // log2(2*pi)

typedef float f4  __attribute__((ext_vector_type(4),  aligned(16)));
typedef float f16v __attribute__((ext_vector_type(16), aligned(64)));
typedef short s8v __attribute__((ext_vector_type(8),  aligned(16)));
typedef short s4v __attribute__((ext_vector_type(4),  aligned(8)));

__device__ __forceinline__ short f2bf(float x) {
    union { __hip_bfloat16 b; short s; } u;
    u.b = __float2bfloat16(x);
    return u.s;
}
__device__ __forceinline__ float bf2f(short s) {
    union { unsigned u; float f; } v;
    v.u = ((unsigned)(unsigned short)s) << 16;
    return v.f;
}
// truncation pack of two NON-NEGATIVE floats to packed bf16 (3 ops)
__device__ __forceinline__ unsigned pk2t(float a, float b) {
    union { float f; unsigned u; } ua, ub;
    ua.f = a; ub.f = b;
    return (ub.u & 0xFFFF0000u) | (ua.u >> 16);
}
__device__ __forceinline__ void gl_lds16(const void* g, void* l) {
    __builtin_amdgcn_global_load_lds(
        (const __attribute__((address_space(1))) void*)g,
        (__attribute__((address_space(3))) void*)l, 16, 0, 0);
}
// RoPE angle via revolutions + sinpi/cospi (cheap, ~1e-4 rad class like f32 ref)
__device__ __forceinline__ void rope_sc(float p, float jf, float& s, float& c) {
    const float rev = p * exp2f(-(jf * ROPE_C1 + ROPE_C2));
    const float f2 = 2.0f * (rev - floorf(rev));
    s = sinpif(f2);
    c = cospif(f2);
}

// ---------------------------------------------------------------------------
// f32 -> bf16 bulk convert (hidden_states), 8 elems/thread
// ---------------------------------------------------------------------------
__global__ __launch_bounds__(256) void f32_to_bf16(
    const float* __restrict__ in, short* __restrict__ out)
{
    const int i = (blockIdx.x * 256 + threadIdx.x) * 8;
    f4 a = *(const f4*)(in + i);
    f4 b = *(const f4*)(in + i + 4);
    s8v v;
    v[0] = f2bf(a[0]); v[1] = f2bf(a[1]); v[2] = f2bf(a[2]); v[3] = f2bf(a[3]);
    v[4] = f2bf(b[0]); v[5] = f2bf(b[1]); v[6] = f2bf(b[2]); v[7] = f2bf(b[3]);
    *(s8v*)(out + i) = v;
}

// ---------------------------------------------------------------------------
// MERGED Q/K/V GPTQ GEMM (16x16x32 MFMA). Per-block routing: bc<32 -> q
// (bf16 row, Qg); bc<40 -> k (bf16 row, Kg, pre-rope); else -> v (bf16
// transposed, Vtg). Grid (48,16) = 768 blocks = 3/CU. A staged via gl_lds
// with pre-swizzled source (rule 21); B dequant int4->bf16 reg-staged.
// ---------------------------------------------------------------------------
__global__ __launch_bounds__(256) void gemm_qkv(
    const short* __restrict__ X,
    const int* __restrict__ q_qw, const float* __restrict__ q_sc, const int* __restrict__ q_zr,
    const int* __restrict__ k_qw, const float* __restrict__ k_sc, const int* __restrict__ k_zr,
    const int* __restrict__ v_qw, const float* __restrict__ v_sc, const int* __restrict__ v_zr,
    short* __restrict__ Qg, short* __restrict__ Kg, short* __restrict__ Vtg)
{
    constexpr int BM = 128, BN = 64;
    constexpr int WM = BM / 2, WN = BN / 2, FM = WM / 16, FN = WN / 16;
    __shared__ __align__(16) short As[BM * 64];
    __shared__ __align__(16) short Bs[BN * 64];
    const int tid = threadIdx.x;
    const int l = tid & 63, w = tid >> 6;
    const int l15 = l & 15, l4 = l >> 4;
    const int wr = w >> 1, wc = w & 1;
    const int br = blockIdx.y, bcx = blockIdx.x;

    // --- uniform per-block routing ---
    const int* qw; const float* scales; const int* zeros;
    int OUT, bc, vmode; short* dst;
    if (bcx < 32)      { qw = q_qw; scales = q_sc; zeros = q_zr; OUT = 2048; bc = bcx;      vmode = 0; dst = Qg;  }
    else if (bcx < 40) { qw = k_qw; scales = k_sc; zeros = k_zr; OUT = 512;  bc = bcx - 32; vmode = 0; dst = Kg;  }
    else               { qw = v_qw; scales = v_sc; zeros = v_zr; OUT = 512;  bc = bcx - 40; vmode = 1; dst = Vtg; }

    const int colB = tid % BN;
    const int colg = bc * BN + colB;
    const int prb  = (tid / BN) * (BN / 32);

    f4 acc[FM][FN] = {};

    for (int kt = 0; kt < 32; ++kt) {
        __syncthreads();
        // --- stage A (BM x 64 bf16) via gl_lds; source pre-swizzled ---
        #pragma unroll
        for (int n = 0; n < BM / 32; ++n) {
            int s = n * 256 + tid;            // 16B-unit index
            int r = s >> 3, up = s & 7;
            int u = up ^ (r & 7);
            gl_lds16(X + (size_t)(br * BM + r) * 2048 + kt * 64 + u * 8,
                     &As[(n * 256 + (tid & ~63)) * 8]);
        }
        // --- stage B: dequant int4 -> bf16, store B^T [BN][64] swizzled ---
        {
            const int g = kt >> 1;
            const float sc = scales[g * OUT + colg];
            const float zf = (float)zeros[g * OUT + colg];
            #pragma unroll
            for (int n = 0; n < BN / 32; ++n) {
                int pr = prb + n;
                unsigned p = (unsigned)qw[(kt * 8 + pr) * OUT + colg];
                s8v bv;
                #pragma unroll
                for (int s = 0; s < 8; ++s) {
                    float qv = (float)((p >> (4 * s)) & 15u);
                    bv[s] = f2bf((qv - zf) * sc);
                }
                *(s8v*)(&Bs[colB * 64 + ((pr * 8) ^ ((colB & 7) << 3))]) = bv;
            }
        }
        __syncthreads();
        #pragma unroll
        for (int ks = 0; ks < 2; ++ks) {
            s8v a[FM], b[FN];
            #pragma unroll
            for (int m_ = 0; m_ < FM; ++m_) {
                int row = wr * WM + m_ * 16 + l15;
                a[m_] = *(const s8v*)(&As[row * 64 + ((ks * 32 + l4 * 8) ^ ((row & 7) << 3))]);
            }
            #pragma unroll
            for (int n_ = 0; n_ < FN; ++n_) {
                int col = wc * WN + n_ * 16 + l15;
                b[n_] = *(const s8v*)(&Bs[col * 64 + ((ks * 32 + l4 * 8) ^ ((col & 7) << 3))]);
            }
            __builtin_amdgcn_s_setprio(1);
            #pragma unroll
            for (int m_ = 0; m_ < FM; ++m_)
                #pragma unroll
                for (int n_ = 0; n_ < FN; ++n_)
                    acc[m_][n_] = __builtin_amdgcn_mfma_f32_16x16x32_bf16(
                        a[m_], b[n_], acc[m_][n_], 0, 0, 0);
            __builtin_amdgcn_s_setprio(0);
        }
    }
    if (vmode == 0) {       // bf16 row-major (Qg or pre-rope Kg)
        #pragma unroll
        for (int m_ = 0; m_ < FM; ++m_)
            #pragma unroll
            for (int n_ = 0; n_ < FN; ++n_)
                #pragma unroll
                for (int r = 0; r < 4; ++r)
                    dst[(size_t)(br * BM + wr * WM + m_ * 16 + l4 * 4 + r) * OUT
                        + bc * BN + wc * WN + n_ * 16 + l15] = f2bf(acc[m_][n_][r]);
    } else {                // bf16 transposed (Vtg [OUT][TSEQ])
        #pragma unroll
        for (int m_ = 0; m_ < FM; ++m_)
            #pragma unroll
            for (int n_ = 0; n_ < FN; ++n_) {
                int col  = bc * BN + wc * WN + n_ * 16 + l15;
                int row0 = br * BM + wr * WM + m_ * 16 + l4 * 4;
                s4v pk;
                #pragma unroll
                for (int r = 0; r < 4; ++r) pk[r] = f2bf(acc[m_][n_][r]);
                *(s4v*)(&dst[(size_t)col * TSEQ + row0]) = pk;
            }
    }
}

// ---------------------------------------------------------------------------
// O-projection GPTQ GEMM (16x16x32), f32 row-major out.
// Grid (32,16) = 512 = 2/CU.
// ---------------------------------------------------------------------------
__global__ __launch_bounds__(256) void gemm_o(
    const short* __restrict__ X, const int* __restrict__ qw,
    const float* __restrict__ scales, const int* __restrict__ zeros,
    float* __restrict__ Y, int OUT)
{
    constexpr int BM = 128, BN = 64;
    constexpr int WM = BM / 2, WN = BN / 2, FM = WM / 16, FN = WN / 16;
    __shared__ __align__(16) short As[BM * 64];
    __shared__ __align__(16) short Bs[BN * 64];
    const int tid = threadIdx.x;
    const int l = tid & 63, w = tid >> 6;
    const int l15 = l & 15, l4 = l >> 4;
    const int wr = w >> 1, wc = w & 1;
    const int br = blockIdx.y, bc = blockIdx.x;

    const int colB = tid % BN;
    const int colg = bc * BN + colB;
    const int prb  = (tid / BN) * (BN / 32);

    f4 acc[FM][FN] = {};

    for (int kt = 0; kt < 32; ++kt) {
        __syncthreads();
        #pragma unroll
        for (int n = 0; n < BM / 32; ++n) {
            int s = n * 256 + tid;
            int r = s >> 3, up = s & 7;
            int u = up ^ (r & 7);
            gl_lds16(X + (size_t)(br * BM + r) * 2048 + kt * 64 + u * 8,
                     &As[(n * 256 + (tid & ~63)) * 8]);
        }
        {
            const int g = kt >> 1;
            const float sc = scales[g * OUT + colg];
            const float zf = (float)zeros[g * OUT + colg];
            #pragma unroll
            for (int n = 0; n < BN / 32; ++n) {
                int pr = prb + n;
                unsigned p = (unsigned)qw[(kt * 8 + pr) * OUT + colg];
                s8v bv;
                #pragma unroll
                for (int s = 0; s < 8; ++s) {
                    float qv = (float)((p >> (4 * s)) & 15u);
                    bv[s] = f2bf((qv - zf) * sc);
                }
                *(s8v*)(&Bs[colB * 64 + ((pr * 8) ^ ((colB & 7) << 3))]) = bv;
            }
        }
        __syncthreads();
        #pragma unroll
        for (int ks = 0; ks < 2; ++ks) {
            s8v a[FM], b[FN];
            #pragma unroll
            for (int m_ = 0; m_ < FM; ++m_) {
                int row = wr * WM + m_ * 16 + l15;
                a[m_] = *(const s8v*)(&As[row * 64 + ((ks * 32 + l4 * 8) ^ ((row & 7) << 3))]);
            }
            #pragma unroll
            for (int n_ = 0; n_ < FN; ++n_) {
                int col = wc * WN + n_ * 16 + l15;
                b[n_] = *(const s8v*)(&Bs[col * 64 + ((ks * 32 + l4 * 8) ^ ((col & 7) << 3))]);
            }
            __builtin_amdgcn_s_setprio(1);
            #pragma unroll
            for (int m_ = 0; m_ < FM; ++m_)
                #pragma unroll
                for (int n_ = 0; n_ < FN; ++n_)
                    acc[m_][n_] = __builtin_amdgcn_mfma_f32_16x16x32_bf16(
                        a[m_], b[n_], acc[m_][n_], 0, 0, 0);
            __builtin_amdgcn_s_setprio(0);
        }
    }
    #pragma unroll
    for (int m_ = 0; m_ < FM; ++m_)
        #pragma unroll
        for (int n_ = 0; n_ < FN; ++n_)
            #pragma unroll
            for (int r = 0; r < 4; ++r)
                Y[(size_t)(br * BM + wr * WM + m_ * 16 + l4 * 4 + r) * OUT
                  + bc * BN + wc * WN + n_ * 16 + l15] = acc[m_][n_][r];
}

// ---------------------------------------------------------------------------
// RoPE (NeoX): Q and K in-place on bf16 (Q additionally prescaled by
// SCALING*LOG2E). Per block t: 16 q-heads (4/thread-group) + 4 k-heads.
// ---------------------------------------------------------------------------
__global__ __launch_bounds__(256) void rope_qk(
    const int* __restrict__ pos, short* __restrict__ Qg, short* __restrict__ Kg)
{
    const int t = blockIdx.x;
    const int tid = threadIdx.x;
    const int j = tid & 63;
    const int g = tid >> 6;
    const float p = (float)pos[t];
    float s, c;
    rope_sc(p, (float)j, s, c);
    const float QS = SCALING * LOG2E;
    #pragma unroll
    for (int n = 0; n < 4; ++n) {
        int h = g * 4 + n;
        short* base = Qg + (size_t)t * 2048 + h * 128;
        float x1 = bf2f(base[j]), x2 = bf2f(base[j + 64]);
        base[j]      = f2bf((x1 * c - x2 * s) * QS);
        base[j + 64] = f2bf((x2 * c + x1 * s) * QS);
    }
    {
        short* base = Kg + (size_t)t * 512 + g * 128;
        float x1 = bf2f(base[j]), x2 = bf2f(base[j + 64]);
        base[j]      = f2bf(x1 * c - x2 * s);
        base[j + 64] = f2bf(x2 * c + x1 * s);
    }
}

// ---------------------------------------------------------------------------
// Swapped-operand 32x32 MFMA flash attention (best measured config, R16/R20:
// 76.7-77.4 µs). 4 waves = 4 q-heads of one GQA group; tile = 32 q-rows;
// KVBLK=64 dbuf gl_lds staging; balanced complementary-pair flat grid
// (f, f+256 co-resident on one CU get complementary jt -> constant per-CU
// work); K-SPLIT=2; Q pre-roped+prescaled; T13 defer-max; T5 setprio; diag
// skip; trunc P-pack. launch_bounds(256,2) — never force waves/EU (R8/R10:
// catastrophic spill). Falsified alternatives: single-buf (R11), KVBLK=32
// (R13), 8-wave (R17), split 3/4 (R9/R17/R21), V-direct (R21) — all >= 77.
// D layout (32x32): col=lane&31, row=(reg&3)+8*(reg>>2)+4*(lane>>5).
// ---------------------------------------------------------------------------
__global__ __launch_bounds__(256, 2) void attn4w(
    const short* __restrict__ Qg, const short* __restrict__ Kg,
    const short* __restrict__ Vtg, short* __restrict__ Op0,
    short* __restrict__ Op1, float2* __restrict__ stats)
{
    __shared__ __align__(16) short Ks[2][64 * 128];   // 2 x 16KB
    __shared__ __align__(16) short Vs[2][128 * 64];   // 2 x 16KB

    const int tid = threadIdx.x;
    const int l = tid & 63, w = tid >> 6;
    const int h = l >> 5, q = l & 31;
    const int f = blockIdx.x;             // flat 0..511
    const int z = f & 1;
    const int kvh = (f >> 1) & 3;
    const int u = f >> 3;                 // 0..63
    const int jt = (u < 32) ? (63 - u) : (u - 32);
    const int q0 = jt * 32;
    const int head = kvh * 4 + w;
    const int row = q0 + q;

    const int nch = (jt >> 1) + 1;        // 64-key chunks for this tile
    const int c0 = (nch * z) >> 1;
    const int c1 = (nch * (z + 1)) >> 1;

    // --- Q fragments: pre-roped, pre-scaled (log2 domain) ---
    s8v qf[8];
    {
        const short* qp = Qg + (size_t)row * 2048 + head * 128 + h * 8;
        #pragma unroll
        for (int d8 = 0; d8 < 8; ++d8) qf[d8] = *(const s8v*)(qp + d8 * 16);
    }

    f16v O[4];
    #pragma unroll
    for (int dt = 0; dt < 4; ++dt)
        #pragma unroll
        for (int r = 0; r < 16; ++r) O[dt][r] = 0.0f;
    float m = -1e30f, lsum = 0.0f;

    if (c0 < c1) {
        // ---- hoisted per-thread staging sources (advance by stride/chunk) ----
        const short* kS[4]; const short* vS[4]; int kD[4], vD[4];
        #pragma unroll
        for (int n4 = 0; n4 < 4; ++n4) {
            int n = w * 4 + n4;
            int s = n * 64 + l;              // K 16B-unit index
            int r = s >> 4, uu = (s & 15) ^ (r & 15);
            kS[n4] = Kg + ((size_t)(c0 * 64 + r) * 512 + kvh * 128 + uu * 8);
            kD[n4] = n * 512;
            int d = s >> 3, uv = (s & 7) ^ (d & 7);
            vS[n4] = Vtg + ((size_t)(kvh * 128 + d) * TSEQ + c0 * 64 + uv * 8);
            vD[n4] = n * 512;
        }
        auto STAGE = [&](int b, int adv) {
            #pragma unroll
            for (int n4 = 0; n4 < 4; ++n4)
                gl_lds16(kS[n4] + (size_t)adv * 32768, &Ks[b][kD[n4]]);
            #pragma unroll
            for (int n4 = 0; n4 < 4; ++n4)
                gl_lds16(vS[n4] + adv * 64, &Vs[b][vD[n4]]);
        };

        STAGE(0, 0);
        int cur = 0;
        for (int kc = c0; kc < c1; ++kc) {
            const int k0 = kc * 64;
            __syncthreads();   // staged data visible; prev buffer free
            if (kc + 1 < c1) STAGE(cur ^ 1, kc + 1 - c0);

            const bool diag  = (kc == nch - 1);
            const bool skip1 = diag && ((jt & 1) == 0);  // upper 32 keys all masked

            // --- QK^T swapped: pD[t] = S[k-tile t][q-row] ---
            f16v pD[2];
            #pragma unroll
            for (int t = 0; t < 2; ++t)
                #pragma unroll
                for (int r = 0; r < 16; ++r) pD[t][r] = 0.0f;
            __builtin_amdgcn_s_setprio(1);
            #pragma unroll
            for (int d8 = 0; d8 < 8; ++d8) {
                s8v kf = *(const s8v*)(
                    &Ks[cur][(q * 16 + ((d8 * 2 + h) ^ (q & 15))) * 8]);
                pD[0] = __builtin_amdgcn_mfma_f32_32x32x16_bf16(kf, qf[d8], pD[0], 0, 0, 0);
            }
            if (!skip1) {
                #pragma unroll
                for (int d8 = 0; d8 < 8; ++d8) {
                    int r = 32 + q;
                    s8v kf = *(const s8v*)(
                        &Ks[cur][(r * 16 + ((d8 * 2 + h) ^ (r & 15))) * 8]);
                    pD[1] = __builtin_amdgcn_mfma_f32_32x32x16_bf16(kf, qf[d8], pD[1], 0, 0, 0);
                }
            }
            __builtin_amdgcn_s_setprio(0);
            if (skip1) {
                #pragma unroll
                for (int r = 0; r < 16; ++r) pD[1][r] = -1e30f;
            }
            // --- causal mask (global last chunk; only the z covering it) ---
            if (diag) {
                #pragma unroll
                for (int t = 0; t < 2; ++t)
                    #pragma unroll
                    for (int r = 0; r < 16; ++r) {
                        int koff = (r & 3) + 8 * (r >> 2) + 4 * h + 32 * t;
                        if (k0 + koff > row) pD[t][r] = -1e30f;
                    }
            }
            // --- row max: lane-local tree + one cross-half shfl ---
            float mx = pD[0][0];
            #pragma unroll
            for (int r = 1; r < 16; ++r) mx = fmaxf(mx, pD[0][r]);
            #pragma unroll
            for (int r = 0; r < 16; ++r) mx = fmaxf(mx, pD[1][r]);
            mx = fmaxf(mx, __shfl_xor(mx, 32, 64));
            // --- T13 defer-max ---
            if (__any(mx - m > 8.0f)) {
                const float mn = fmaxf(m, mx);
                const float sc = exp2f(m - mn);
                #pragma unroll
                for (int dt = 0; dt < 4; ++dt)
                    #pragma unroll
                    for (int r = 0; r < 16; ++r) O[dt][r] *= sc;
                lsum *= sc;
                m = mn;
            }
            // --- P = exp2(S - m) (bounded by 2^8), row sum ---
            float rs = 0.0f;
            #pragma unroll
            for (int t = 0; t < 2; ++t)
                #pragma unroll
                for (int r = 0; r < 16; ++r) {
                    float pv = exp2f(pD[t][r] - m);
                    pD[t][r] = pv;
                    rs += pv;
                }
            rs += __shfl_xor(rs, 32, 64);
            lsum += rs;
            // --- pack P -> bf16 B-fragments (trunc pack, quad exchange) ---
            s8v pf[4];
            #pragma unroll
            for (int s = 0; s < 4; ++s) {
                const int t = s >> 1, c = s & 1;
                const int bk = 8 * c + 4 * h;
                const int bs = 8 * c + 4 * (1 - h);
                unsigned kp0 = pk2t(pD[t][bk + 0], pD[t][bk + 1]);
                unsigned kp1 = pk2t(pD[t][bk + 2], pD[t][bk + 3]);
                unsigned sp0 = pk2t(pD[t][bs + 0], pD[t][bs + 1]);
                unsigned sp1 = pk2t(pD[t][bs + 2], pD[t][bs + 3]);
                unsigned r0 = __shfl_xor((int)sp0, 32, 64);
                unsigned r1 = __shfl_xor((int)sp1, 32, 64);
                union { unsigned u[4]; s8v v; } fr;
                fr.u[0] = h ? r0 : kp0;
                fr.u[1] = h ? r1 : kp1;
                fr.u[2] = h ? kp0 : r0;
                fr.u[3] = h ? kp1 : r1;
                pf[s] = fr.v;
            }
            // --- PV swapped: O^T[dt] += Vt-frag * P^T-frag ---
            __builtin_amdgcn_s_setprio(1);
            #pragma unroll
            for (int s = 0; s < 4; ++s) {
                if (!(skip1 && s >= 2)) {
                    #pragma unroll
                    for (int dt = 0; dt < 4; ++dt) {
                        int rv = dt * 32 + q;
                        s8v vf = *(const s8v*)(
                            &Vs[cur][(rv * 8 + ((2 * s + h) ^ (rv & 7))) * 8]);
                        O[dt] = __builtin_amdgcn_mfma_f32_32x32x16_bf16(vf, pf[s], O[dt], 0, 0, 0);
                    }
                }
            }
            __builtin_amdgcn_s_setprio(0);
            cur ^= 1;
        }
    }

    // --- epilogue: UNNORMALIZED partial O (bf16) + stats ---
    short* Opz = z ? Op1 : Op0;
    #pragma unroll
    for (int dt = 0; dt < 4; ++dt)
        #pragma unroll
        for (int g2 = 0; g2 < 4; ++g2) {
            int d4 = dt * 32 + 8 * g2 + 4 * h;
            s4v ov;
            #pragma unroll
            for (int r = 0; r < 4; ++r) ov[r] = f2bf(O[dt][g2 * 4 + r]);
            *(s4v*)(Opz + (size_t)row * 2048 + head * 128 + d4) = ov;
        }
    if (h == 0)
        stats[((size_t)z * NH + head) * TSEQ + row] = make_float2(m, lsum);
}

// ---------------------------------------------------------------------------
// Combine the two K-split partials. out may alias Op0.
// ---------------------------------------------------------------------------
__global__ __launch_bounds__(256) void attn_combine2(
    const short* __restrict__ Op0, const short* __restrict__ Op1,
    const float2* __restrict__ stats, short* __restrict__ out)
{
    const int gp = blockIdx.x * 16 + (threadIdx.x >> 4);   // row*16 + head
    const int row = gp >> 4;
    const int head = gp & 15;
    const int d0 = (threadIdx.x & 15) * 8;
    const float2 s0 = stats[(size_t)head * TSEQ + row];
    const float2 s1 = stats[((size_t)NH + head) * TSEQ + row];
    const float M = fmaxf(s0.x, s1.x);
    const float w0 = exp2f(s0.x - M), w1 = exp2f(s1.x - M);
    const float inv = 1.0f / (s0.y * w0 + s1.y * w1);
    const size_t off = (size_t)row * 2048 + head * 128 + d0;
    s8v a = *(const s8v*)(Op0 + off);
    s8v b = *(const s8v*)(Op1 + off);
    s8v o;
    #pragma unroll
    for (int j = 0; j < 8; ++j)
        o[j] = f2bf((bf2f(a[j]) * w0 + bf2f(b[j]) * w1) * inv);
    *(s8v*)(out + off) = o;
}

// ---------------------------------------------------------------------------
extern "C" void kernel_launch(void* const* d_in, const int* in_sizes, int n_in,
                              void* d_out, int out_size, void* d_ws, size_t ws_size,
                              hipStream_t stream)
{
    const int*   positions = (const int*)  d_in[0];
    const float* hidden    = (const float*)d_in[1];
    const int*   q_qw = (const int*)  d_in[2];
    const float* q_sc = (const float*)d_in[3];
    const int*   q_zr = (const int*)  d_in[4];
    const int*   k_qw = (const int*)  d_in[5];
    const float* k_sc = (const float*)d_in[6];
    const int*   k_zr = (const int*)  d_in[7];
    const int*   v_qw = (const int*)  d_in[8];
    const float* v_sc = (const float*)d_in[9];
    const int*   v_zr = (const int*)  d_in[10];
    const int*   o_qw = (const int*)  d_in[11];
    const float* o_sc = (const float*)d_in[12];
    const int*   o_zr = (const int*)  d_in[13];
    float* outf = (float*)d_out;

    // workspace (40 MB), lifetime-based aliasing:
    //  [0,8M):   Qg bf16[T,2048]  (gemm_qkv out; rope_qk in-place; attn in)
    //  [8,16M):  Op0 bf16 (attn partial z0) -> abuf (combine out, in-place)
    //  [16,20M): stats float2[2][NH][T]
    //  [20,28M): hb bf16[2048,2048] (dead after gemm_qkv) -> Op1
    //  [28,30M): Kg bf16[T,512]   (gemm_qkv out, rope_qk in-place)
    //  [30,32M): Vtg bf16[512,T]  (gemm_qkv transposed out)
    char* base = (char*)d_ws;
    short* Qg   = (short*)(base);
    short* Op0  = (short*)(base + (8u << 20));
    short* abuf = Op0;
    float2* stats = (float2*)(base + (16u << 20));
    short* hb   = (short*)(base + (20u << 20));
    short* Op1  = (short*)(base + (20u << 20));
    short* Kg   = (short*)(base + (28u << 20));
    short* Vtg  = (short*)(base + (30u << 20));

    dim3 blk(256);
    f32_to_bf16<<<dim3(2048), blk, 0, stream>>>(hidden, hb);
    gemm_qkv<<<dim3(48, 16), blk, 0, stream>>>(hb,
        q_qw, q_sc, q_zr, k_qw, k_sc, k_zr, v_qw, v_sc, v_zr, Qg, Kg, Vtg);
    rope_qk<<<dim3(TSEQ), blk, 0, stream>>>(positions, Qg, Kg);
    attn4w<<<dim3(512), blk, 0, stream>>>(Qg, Kg, Vtg, Op0, Op1, stats);
    attn_combine2<<<dim3(TSEQ * NH / 16), blk, 0, stream>>>(Op0, Op1, stats, abuf);
    gemm_o<<<dim3(32, 16), blk, 0, stream>>>(abuf, o_qw, o_sc, o_zr, outf, 2048);
}